// Round 8
// baseline (909.353 us; speedup 1.0000x reference)
//
#include <hip/hip_runtime.h>
#include <hip/hip_bf16.h>

typedef __hip_bfloat16 bf16;

#define N_NODES 100000
#define N_EDGES 1600000
#define F_IN    128
#define F_OUT   64
#define NBLK    391   // ceil(100000/256)

#define NB_BKT   391    // buckets of 256 target-nodes (c>>8)
#define BKT_SH   8
#define BKT_CAP  4608   // expected 4096/bucket, +8 sigma
#define LBIN_CAP 32     // per-block LDS bin cap (expected 10.5, +6.6 sigma)
#define EPB_A    4096   // edges per block, phase A

// ---------------- CSR-free path workspace layout (bytes) ----------------
// flag @0 (256) | M @256 (32KB) | cvec @33,024 | gtail @33,280 (1564B)
// dinv f32 @35,072 (400KB, ends 435,072)
// bkt u32 @435,072 (391*4608*4 = 7,206,912, ends 7,641,984)
// y bf16 @7,641,984 (12.8MB, ends 20,441,984)
// total 20,441,984 B. Fallback (atomic multi-pass) path used if ws smaller.

__device__ __forceinline__ float ldf(const void* p, size_t i, bool isbf) {
    return isbf ? __bfloat162float(((const bf16*)p)[i]) : ((const float*)p)[i];
}
__device__ __forceinline__ void stf(void* p, size_t i, bool isbf, float v) {
    if (isbf) ((bf16*)p)[i] = __float2bfloat16(v);
    else      ((float*)p)[i] = v;
}
__device__ __forceinline__ unsigned short f2bfu(float f) {
    __hip_bfloat16 h = __float2bfloat16(f);
    union { __hip_bfloat16 h; unsigned short u; } c; c.h = h; return c.u;
}
__device__ __forceinline__ float bflo(unsigned int u) { return __uint_as_float(u << 16); }
__device__ __forceinline__ float bfhi(unsigned int u) { return __uint_as_float(u & 0xffff0000u); }

// dtype sniff (bf16 vs fp32 world), 64-lane parallel + ballot reduce.
__global__ void k_detect(const unsigned short* __restrict__ w, int* __restrict__ flag) {
    int l = threadIdx.x;
    int good = 0;
#pragma unroll
    for (int q = 0; q < 2; ++q) {
        unsigned short v = w[2 * (l + 64 * q)];
        int e = (v >> 7) & 0xFF;
        if ((e >= 100 && e <= 140) || ((v & 0x7FFF) == 0)) good++;
    }
    unsigned long long m1 = __ballot(good >= 1), m2 = __ballot(good >= 2);
    if (l == 0) *flag = (__popcll(m1) + __popcll(m2) >= 96) ? 1 : 0;
}

// M = W_gcn @ W_fc^T (128x64), cvec = W_fc @ b_gcn + b_fc
__global__ void k_weights(const int* __restrict__ flag,
                          const void* __restrict__ Wg, const void* __restrict__ bg,
                          const void* __restrict__ Wf, const void* __restrict__ bfc,
                          float* __restrict__ M, float* __restrict__ cvec) {
    bool isbf = (*flag != 0);
    int t = blockIdx.x * blockDim.x + threadIdx.x;
    if (t >= F_IN * F_OUT) return;
    int k = t >> 6, c = t & 63;
    float s = 0.f;
    for (int j = 0; j < F_IN; ++j)
        s += ldf(Wg, k * F_IN + j, isbf) * ldf(Wf, c * F_IN + j, isbf);
    M[k * F_OUT + c] = s;
    if (k == 0) {
        float cs = ldf(bfc, c, isbf);
        for (int j = 0; j < F_IN; ++j)
            cs += ldf(bg, j, isbf) * ldf(Wf, c * F_IN + j, isbf);
        cvec[c] = cs;
    }
}

// ===================== CSR-free bucket path =====================

__global__ void k_zero(int* __restrict__ gtail) {
    int i = blockIdx.x * 256 + threadIdx.x;
    if (i < NB_BKT) gtail[i] = 0;
}

// phase A: bucketize edges by target>>8 with LDS binning, coalesced flush.
// entry = src (17b) | (c & 255) << 17
__global__ __launch_bounds__(256) void k_binA(const int* __restrict__ ei,
                                              int* __restrict__ gtail,
                                              unsigned* __restrict__ bkt) {
    __shared__ unsigned lbin[NB_BKT * LBIN_CAP];
    __shared__ int lcnt[NB_BKT];
    __shared__ int lbase[NB_BKT];
    int t = threadIdx.x;
    for (int b = t; b < NB_BKT; b += 256) lcnt[b] = 0;
    __syncthreads();
    int e0 = blockIdx.x * EPB_A;
#pragma unroll
    for (int q = 0; q < EPB_A / 256; ++q) {
        int e = e0 + q * 256 + t;
        if (e < N_EDGES) {
            int r = ei[e], c = ei[N_EDGES + e];
            int b = c >> BKT_SH;
            unsigned val = (unsigned)r | ((unsigned)(c & ((1 << BKT_SH) - 1)) << 17);
            int p = atomicAdd(&lcnt[b], 1);
            if (p < LBIN_CAP) {
                lbin[b * LBIN_CAP + p] = val;
            } else {                          // rare overflow: direct global
                int gp = atomicAdd(&gtail[b], 1);
                if (gp < BKT_CAP) bkt[(size_t)b * BKT_CAP + gp] = val;
            }
        }
    }
    __syncthreads();
    for (int b = t; b < NB_BKT; b += 256) {
        int n = min(lcnt[b], LBIN_CAP);
        lbase[b] = atomicAdd(&gtail[b], n);
    }
    __syncthreads();
    for (int idx = t; idx < NB_BKT * LBIN_CAP; idx += 256) {
        int b = idx / LBIN_CAP, i = idx - b * LBIN_CAP;
        if (i < min(lcnt[b], LBIN_CAP)) {
            int gp = lbase[b] + i;
            if (gp < BKT_CAP) bkt[(size_t)b * BKT_CAP + gp] = lbin[idx];
        }
    }
}

// per-bucket degree -> dinv (LDS histogram, no global atomics)
__global__ __launch_bounds__(256) void k_bdeg(const unsigned* __restrict__ bkt,
                                              const int* __restrict__ gtail,
                                              float* __restrict__ dinv) {
    __shared__ int cntl[256];
    int b = blockIdx.x, t = threadIdx.x;
    int n = min(gtail[b], BKT_CAP);
    cntl[t] = 0;
    __syncthreads();
    for (int i = t; i < n; i += 256)
        atomicAdd(&cntl[bkt[(size_t)b * BKT_CAP + i] >> 17], 1);
    __syncthreads();
    int node = (b << BKT_SH) + t;
    if (node < N_NODES) dinv[node] = rsqrtf((float)(cntl[t] + 1));  // +1 self-loop
}

// y = dinv[r] * (x @ M), bf16 into ws. 64 rows/block, 4x4 register tile.
__global__ __launch_bounds__(256) void k_xmz(const int* __restrict__ flag,
                                             const void* __restrict__ x,
                                             const float* __restrict__ M,
                                             const float* __restrict__ dinv,
                                             bf16* __restrict__ y) {
    __shared__ float4 Ms4[F_IN * 16];   // [k*16 + cg]
    __shared__ float4 xs4[32 * 64];     // [k4*64 + (row^(k4&7))]
    int t = threadIdx.x;
    bool isbf = (*flag != 0);
    int r0 = blockIdx.x * 64;

#pragma unroll
    for (int q = 0; q < 8; ++q) {
        int i = q * 256 + t;
        Ms4[i] = ((const float4*)M)[i];
    }
    if (isbf) {
        const unsigned short* xb = (const unsigned short*)x;
#pragma unroll
        for (int q = 0; q < 4; ++q) {
            int idx = q * 256 + t;
            int row = idx >> 4, c8 = idx & 15;
            int rr = min(r0 + row, N_NODES - 1);
            uint4 u = ((const uint4*)(xb + (size_t)rr * F_IN))[c8];
            float4 v0 = make_float4(bflo(u.x), bfhi(u.x), bflo(u.y), bfhi(u.y));
            float4 v1 = make_float4(bflo(u.z), bfhi(u.z), bflo(u.w), bfhi(u.w));
            int k40 = c8 * 2, k41 = c8 * 2 + 1;
            xs4[k40 * 64 + (row ^ (k40 & 7))] = v0;
            xs4[k41 * 64 + (row ^ (k41 & 7))] = v1;
        }
    } else {
        const float* xf = (const float*)x;
#pragma unroll
        for (int q = 0; q < 8; ++q) {
            int idx = q * 256 + t;
            int row = idx >> 5, k4 = idx & 31;
            int rr = min(r0 + row, N_NODES - 1);
            float4 v = ((const float4*)(xf + (size_t)rr * F_IN))[k4];
            xs4[k4 * 64 + (row ^ (k4 & 7))] = v;
        }
    }
    __syncthreads();

    int cg = t & 15;
    int rs = t >> 4;
    float4 a0 = {0,0,0,0}, a1 = {0,0,0,0}, a2 = {0,0,0,0}, a3 = {0,0,0,0};

    for (int k4 = 0; k4 < 32; ++k4) {
        float4 m0 = Ms4[(k4 * 4 + 0) * 16 + cg];
        float4 m1 = Ms4[(k4 * 4 + 1) * 16 + cg];
        float4 m2 = Ms4[(k4 * 4 + 2) * 16 + cg];
        float4 m3 = Ms4[(k4 * 4 + 3) * 16 + cg];
        int sw = k4 & 7;
#pragma unroll
        for (int i = 0; i < 4; ++i) {
            int row = rs * 4 + i;
            float4 xv = xs4[k4 * 64 + (row ^ sw)];
            float4* a = (i == 0) ? &a0 : (i == 1) ? &a1 : (i == 2) ? &a2 : &a3;
            a->x += xv.x * m0.x + xv.y * m1.x + xv.z * m2.x + xv.w * m3.x;
            a->y += xv.x * m0.y + xv.y * m1.y + xv.z * m2.y + xv.w * m3.y;
            a->z += xv.x * m0.z + xv.y * m1.z + xv.z * m2.z + xv.w * m3.z;
            a->w += xv.x * m0.w + xv.y * m1.w + xv.z * m2.w + xv.w * m3.w;
        }
    }

    float4 av[4] = {a0, a1, a2, a3};
#pragma unroll
    for (int i = 0; i < 4; ++i) {
        int row = r0 + rs * 4 + i;
        if (row < N_NODES) {
            float d = dinv[row];
            ushort4 pk;
            pk.x = f2bfu(av[i].x * d); pk.y = f2bfu(av[i].y * d);
            pk.z = f2bfu(av[i].z * d); pk.w = f2bfu(av[i].w * d);
            ((ushort4*)((unsigned short*)y + (size_t)row * F_OUT))[cg] = pk;
        }
    }
}

// per-bucket aggregation in LDS: acc[256 nodes x 64 feat] fp32 (64 KB).
// out[c] = dinv[c] * (sum_{edges r->c} y[r] + y[c]) + cvec
__global__ __launch_bounds__(512) void k_megaagg(const int* __restrict__ flag,
                                                 const unsigned* __restrict__ bkt,
                                                 const int* __restrict__ gtail,
                                                 const float* __restrict__ dinv,
                                                 const bf16* __restrict__ y,
                                                 const float* __restrict__ cvec,
                                                 void* __restrict__ out) {
    __shared__ float acc[256 * F_OUT];   // 64 KB
    int b = blockIdx.x, t = threadIdx.x;
    int n = min(gtail[b], BKT_CAP);
    float4* acc4 = (float4*)acc;
#pragma unroll
    for (int i = 0; i < 8; ++i) acc4[i * 512 + t] = make_float4(0.f, 0.f, 0.f, 0.f);
    __syncthreads();

    const unsigned short* yu = (const unsigned short*)y;
    int wave = t >> 6, lane = t & 63;
    for (int c0 = wave * 64; c0 < n; c0 += 8 * 64) {
        int m = min(64, n - c0);
        unsigned ent = 0;
        if (lane < m) ent = bkt[(size_t)b * BKT_CAP + c0 + lane];
        int k = 0;
        for (; k + 8 <= m; k += 8) {
            unsigned e8[8]; float v8[8];
#pragma unroll
            for (int u = 0; u < 8; ++u) {
                e8[u] = __shfl(ent, k + u, 64);
                int src = (int)(e8[u] & 0x1FFFF);
                v8[u] = __uint_as_float((unsigned)yu[(size_t)src * F_OUT + lane] << 16);
            }
#pragma unroll
            for (int u = 0; u < 8; ++u)
                atomicAdd(&acc[(int)(e8[u] >> 17) * F_OUT + lane], v8[u]);
        }
        for (; k < m; ++k) {
            unsigned e = __shfl(ent, k, 64);
            int src = (int)(e & 0x1FFFF);
            float v = __uint_as_float((unsigned)yu[(size_t)src * F_OUT + lane] << 16);
            atomicAdd(&acc[(int)(e >> 17) * F_OUT + lane], v);
        }
    }
    __syncthreads();

    bool isbf = (*flag != 0);
    int base_node = b << BKT_SH;
    for (int i = t; i < 256 * F_OUT; i += 512) {
        int cl = i >> 6, f = i & 63;
        int node = base_node + cl;
        if (node < N_NODES) {
            float sl = __uint_as_float((unsigned)yu[(size_t)node * F_OUT + f] << 16);
            float v = dinv[node] * (acc[i] + sl) + cvec[f];
            stf(out, (size_t)node * F_OUT + f, isbf, v);
        }
    }
}

// ===================== fallback (atomic multi-pass) path =====================

__global__ void k_init_deg(float* __restrict__ deg) {
    int i = blockIdx.x * blockDim.x + threadIdx.x;
    if (i < N_NODES) deg[i] = 1.0f;
}
__global__ void k_deg(const int* __restrict__ col, float* __restrict__ deg) {
    int e = blockIdx.x * blockDim.x + threadIdx.x;
    if (e < N_EDGES) atomicAdd(&deg[col[e]], 1.0f);
}
__global__ void k_dinv(float* __restrict__ deg) {
    int i = blockIdx.x * blockDim.x + threadIdx.x;
    if (i < N_NODES) deg[i] = rsqrtf(deg[i]);
}
__global__ __launch_bounds__(256) void k_xm(const int* __restrict__ flag,
                                            const void* __restrict__ x,
                                            const float* __restrict__ M,
                                            void* __restrict__ z) {
    __shared__ float Ms[F_IN * F_OUT];
    int t = threadIdx.x;
    for (int i = t; i < F_IN * F_OUT; i += 256) Ms[i] = M[i];
    __syncthreads();
    bool isbf = (*flag != 0);
    int r = blockIdx.x * 4 + (t >> 6);
    int c = t & 63;
    if (r >= N_NODES) return;
    float s = 0.f;
    if (isbf) {
        const bf16* xr = (const bf16*)x + (size_t)r * F_IN;
#pragma unroll
        for (int k = 0; k < F_IN; ++k) s += __bfloat162float(xr[k]) * Ms[k * F_OUT + c];
    } else {
        const float* xr = (const float*)x + (size_t)r * F_IN;
#pragma unroll
        for (int k = 0; k < F_IN; ++k) s += xr[k] * Ms[k * F_OUT + c];
    }
    stf(z, (size_t)r * F_OUT + c, isbf, s);
}
template <int LOGF>
__global__ __launch_bounds__(256) void k_init_acc(const int* __restrict__ flag,
                                                  const float* __restrict__ dinv,
                                                  const void* __restrict__ z,
                                                  float* __restrict__ acc, int base) {
    bool isbf = (*flag != 0);
    int t = blockIdx.x * 256 + threadIdx.x;
    int i = t >> LOGF, f = t & ((1 << LOGF) - 1);
    if (i >= N_NODES) return;
    float d = dinv[i];
    acc[t] = d * d * ldf(z, (size_t)i * F_OUT + base + f, isbf);
}
template <int LOGF>
__global__ __launch_bounds__(256) void k_scatter(const int* __restrict__ flag,
                                                 const int* __restrict__ ei,
                                                 const float* __restrict__ dinv,
                                                 const void* __restrict__ z,
                                                 float* __restrict__ acc, int base) {
    bool isbf = (*flag != 0);
    long long t = (long long)blockIdx.x * 256 + threadIdx.x;
    int e = (int)(t >> LOGF), f = (int)(t & ((1 << LOGF) - 1));
    if (e >= N_EDGES) return;
    int r = ei[e], c = ei[N_EDGES + e];
    float nm = dinv[r] * dinv[c];
    float v  = nm * ldf(z, (size_t)r * F_OUT + base + f, isbf);
    atomicAdd(&acc[((size_t)c << LOGF) + f], v);
}
template <int LOGF>
__global__ __launch_bounds__(256) void k_final(const int* __restrict__ flag,
                                               const float* __restrict__ acc,
                                               const float* __restrict__ cvec,
                                               void* __restrict__ out, int base) {
    bool isbf = (*flag != 0);
    int t = blockIdx.x * 256 + threadIdx.x;
    int i = t >> LOGF, f = t & ((1 << LOGF) - 1);
    if (i >= N_NODES) return;
    stf(out, (size_t)i * F_OUT + base + f, isbf, acc[t] + cvec[base + f]);
}
template <int LOGF>
static void run_passes(const int* flag, const int* ei, const float* dinv,
                       const void* z, float* acc, const float* cvec, void* out,
                       hipStream_t stream) {
    const int fpp = 1 << LOGF;
    const long long tn = (long long)N_NODES * fpp;
    const long long te = (long long)N_EDGES * fpp;
    const int gn = (int)((tn + 255) / 256);
    const int ge = (int)((te + 255) / 256);
    for (int base = 0; base < F_OUT; base += fpp) {
        k_init_acc<LOGF><<<gn, 256, 0, stream>>>(flag, dinv, z, acc, base);
        k_scatter<LOGF><<<ge, 256, 0, stream>>>(flag, ei, dinv, z, acc, base);
        k_final<LOGF><<<gn, 256, 0, stream>>>(flag, acc, cvec, out, base);
    }
}

extern "C" void kernel_launch(void* const* d_in, const int* in_sizes, int n_in,
                              void* d_out, int out_size, void* d_ws, size_t ws_size,
                              hipStream_t stream) {
    const void* x   = d_in[0];
    const int*  ei  = (const int*)d_in[1];
    const void* Wg  = d_in[2];
    const void* bg  = d_in[3];
    const void* Wf  = d_in[4];
    const void* bfc = d_in[5];
    char* ws = (char*)d_ws;

    const size_t NEED = 20441984;
    if (ws_size >= NEED) {
        int*      flag  = (int*)(ws + 0);
        float*    M     = (float*)(ws + 256);
        float*    cvec  = (float*)(ws + 33024);
        int*      gtail = (int*)(ws + 33280);
        float*    dinv  = (float*)(ws + 35072);
        unsigned* bkt   = (unsigned*)(ws + 435072);
        bf16*     y     = (bf16*)(ws + 7641984);

        k_detect<<<1, 64, 0, stream>>>((const unsigned short*)x, flag);
        k_zero<<<2, 256, 0, stream>>>(gtail);
        k_weights<<<(F_IN * F_OUT) / 256, 256, 0, stream>>>(flag, Wg, bg, Wf, bfc, M, cvec);
        k_binA<<<(N_EDGES + EPB_A - 1) / EPB_A, 256, 0, stream>>>(ei, gtail, bkt);
        k_bdeg<<<NB_BKT, 256, 0, stream>>>(bkt, gtail, dinv);
        k_xmz<<<(N_NODES + 63) / 64, 256, 0, stream>>>(flag, x, M, dinv, y);
        k_megaagg<<<NB_BKT, 512, 0, stream>>>(flag, bkt, gtail, dinv, y, cvec, d_out);
    } else {
        int*   flag = (int*)(ws + 0);
        float* deg  = (float*)(ws + 256);
        float* M    = (float*)(ws + 400384);
        float* cvec = (float*)(ws + 433152);
        float* acc  = (float*)(ws + 433664);

        k_detect<<<1, 64, 0, stream>>>((const unsigned short*)x, flag);
        k_init_deg<<<NBLK, 256, 0, stream>>>(deg);
        k_deg<<<N_EDGES / 256, 256, 0, stream>>>(ei + N_EDGES, deg);
        k_dinv<<<NBLK, 256, 0, stream>>>(deg);
        k_weights<<<(F_IN * F_OUT) / 256, 256, 0, stream>>>(flag, Wg, bg, Wf, bfc, M, cvec);
        k_xm<<<N_NODES / 4, 256, 0, stream>>>(flag, x, M, d_out);
        const size_t bn = 433664;
        if      (ws_size >= bn + (400000ull << 6)) run_passes<6>(flag, ei, deg, d_out, acc, cvec, d_out, stream);
        else if (ws_size >= bn + (400000ull << 5)) run_passes<5>(flag, ei, deg, d_out, acc, cvec, d_out, stream);
        else if (ws_size >= bn + (400000ull << 4)) run_passes<4>(flag, ei, deg, d_out, acc, cvec, d_out, stream);
        else if (ws_size >= bn + (400000ull << 3)) run_passes<3>(flag, ei, deg, d_out, acc, cvec, d_out, stream);
        else if (ws_size >= bn + (400000ull << 2)) run_passes<2>(flag, ei, deg, d_out, acc, cvec, d_out, stream);
        else if (ws_size >= bn + (400000ull << 1)) run_passes<1>(flag, ei, deg, d_out, acc, cvec, d_out, stream);
        else                                       run_passes<0>(flag, ei, deg, d_out, acc, cvec, d_out, stream);
    }
}

// Round 9
// 255.174 us; speedup vs baseline: 3.5637x; 3.5637x over previous
//
#include <hip/hip_runtime.h>
#include <hip/hip_bf16.h>

typedef __hip_bfloat16 bf16;

#define N_NODES 100000
#define N_EDGES 1600000
#define F_IN    128
#define F_OUT   64
#define NBLK    391   // ceil(100000/256)

#define NB_BKT   196    // buckets of 512 target-nodes (c>>9)
#define BKT_SH   9
#define BKT_CAP  8960   // expected 8163/bucket, +8.8 sigma
#define LBIN_CAP 56     // per-block LDS bin cap (expected 20.9, +7.7 sigma)
#define EPB_A    4096   // edges per block, phase A

// ---------------- CSR-path workspace layout (bytes) ----------------
// flag @0 (256) | dinv f32 @256 | M @400,384 | cvec @433,152
// cnt @433,664 | ptr @833,664 | gtail @1,233,664 (784B) | bbase @1,234,560
// srcs int @1,238,528 (6.4MB, ends 7,638,528)
// y bf16 @8,038,400 (12.8MB, ends 20,838,400)  [y = dinv[r]*(x@M)]
// bkt u32 @8,038,400 (7.02MB) ALIASES y: bkt dead before k_xmz writes y.
// total 20,838,400 B. Fallback (atomic multi-pass) path used if ws smaller.

__device__ __forceinline__ float ldf(const void* p, size_t i, bool isbf) {
    return isbf ? __bfloat162float(((const bf16*)p)[i]) : ((const float*)p)[i];
}
__device__ __forceinline__ void stf(void* p, size_t i, bool isbf, float v) {
    if (isbf) ((bf16*)p)[i] = __float2bfloat16(v);
    else      ((float*)p)[i] = v;
}
__device__ __forceinline__ unsigned short f2bfu(float f) {
    __hip_bfloat16 h = __float2bfloat16(f);
    union { __hip_bfloat16 h; unsigned short u; } c; c.h = h; return c.u;
}
__device__ __forceinline__ float bflo(unsigned int u) { return __uint_as_float(u << 16); }
__device__ __forceinline__ float bfhi(unsigned int u) { return __uint_as_float(u & 0xffff0000u); }

// dtype sniff (bf16 vs fp32 world), 64-lane parallel + ballot reduce.
__global__ void k_detect(const unsigned short* __restrict__ w, int* __restrict__ flag) {
    int l = threadIdx.x;
    int good = 0;
#pragma unroll
    for (int q = 0; q < 2; ++q) {
        unsigned short v = w[2 * (l + 64 * q)];
        int e = (v >> 7) & 0xFF;
        if ((e >= 100 && e <= 140) || ((v & 0x7FFF) == 0)) good++;
    }
    unsigned long long m1 = __ballot(good >= 1), m2 = __ballot(good >= 2);
    if (l == 0) *flag = (__popcll(m1) + __popcll(m2) >= 96) ? 1 : 0;
}

// M = W_gcn @ W_fc^T (128x64), cvec = W_fc @ b_gcn + b_fc
__global__ void k_weights(const int* __restrict__ flag,
                          const void* __restrict__ Wg, const void* __restrict__ bg,
                          const void* __restrict__ Wf, const void* __restrict__ bfc,
                          float* __restrict__ M, float* __restrict__ cvec) {
    bool isbf = (*flag != 0);
    int t = blockIdx.x * blockDim.x + threadIdx.x;
    if (t >= F_IN * F_OUT) return;
    int k = t >> 6, c = t & 63;
    float s = 0.f;
    for (int j = 0; j < F_IN; ++j)
        s += ldf(Wg, k * F_IN + j, isbf) * ldf(Wf, c * F_IN + j, isbf);
    M[k * F_OUT + c] = s;
    if (k == 0) {
        float cs = ldf(bfc, c, isbf);
        for (int j = 0; j < F_IN; ++j)
            cs += ldf(bg, j, isbf) * ldf(Wf, c * F_IN + j, isbf);
        cvec[c] = cs;
    }
}

// ===================== CSR (atomic-free) path =====================

__global__ void k_zero(int* __restrict__ gtail) {
    int i = threadIdx.x;
    if (i < NB_BKT) gtail[i] = 0;
}

// phase A: bucketize edges by target>>9 with LDS binning, coalesced flush.
// entry = src (17b) | (c & 511) << 17
__global__ __launch_bounds__(256) void k_binA(const int* __restrict__ ei,
                                              int* __restrict__ gtail,
                                              unsigned* __restrict__ bkt) {
    __shared__ unsigned lbin[NB_BKT * LBIN_CAP];
    __shared__ int lcnt[NB_BKT];
    __shared__ int lbase[NB_BKT];
    int t = threadIdx.x;
    for (int b = t; b < NB_BKT; b += 256) lcnt[b] = 0;
    __syncthreads();
    int e0 = blockIdx.x * EPB_A;
#pragma unroll
    for (int q = 0; q < EPB_A / 256; ++q) {
        int e = e0 + q * 256 + t;
        if (e < N_EDGES) {
            int r = ei[e], c = ei[N_EDGES + e];
            int b = c >> BKT_SH;
            unsigned val = (unsigned)r | ((unsigned)(c & ((1 << BKT_SH) - 1)) << 17);
            int p = atomicAdd(&lcnt[b], 1);
            if (p < LBIN_CAP) {
                lbin[b * LBIN_CAP + p] = val;
            } else {                          // rare overflow: direct global
                int gp = atomicAdd(&gtail[b], 1);
                if (gp < BKT_CAP) bkt[(size_t)b * BKT_CAP + gp] = val;
            }
        }
    }
    __syncthreads();
    for (int b = t; b < NB_BKT; b += 256) {
        int n = min(lcnt[b], LBIN_CAP);
        lbase[b] = atomicAdd(&gtail[b], n);
    }
    __syncthreads();
    for (int idx = t; idx < NB_BKT * LBIN_CAP; idx += 256) {
        int b = idx / LBIN_CAP, i = idx - b * LBIN_CAP;
        if (i < min(lcnt[b], LBIN_CAP)) {
            int gp = lbase[b] + i;
            if (gp < BKT_CAP) bkt[(size_t)b * BKT_CAP + gp] = lbin[idx];
        }
    }
}

// exclusive scan of per-bucket totals -> bucket base offsets in srcs
__global__ void k_bktscan(const int* __restrict__ gtail, int* __restrict__ bbase) {
    __shared__ int sm[256];
    int t = threadIdx.x;
    int v = (t < NB_BKT) ? min(gtail[t], BKT_CAP) : 0;
    sm[t] = v; __syncthreads();
    for (int s = 1; s < 256; s <<= 1) {
        int add = (t >= s) ? sm[t - s] : 0;
        __syncthreads();
        sm[t] += add;
        __syncthreads();
    }
    if (t < NB_BKT) bbase[t] = sm[t] - v;
}

// per-bucket: LDS histogram -> LDS scan -> ptr/cnt/dinv -> place srcs.
__global__ __launch_bounds__(512) void k_build(const unsigned* __restrict__ bkt,
                                               const int* __restrict__ gtail,
                                               const int* __restrict__ bbase,
                                               int* __restrict__ ptr,
                                               int* __restrict__ cnt,
                                               float* __restrict__ dinv,
                                               int* __restrict__ srcs) {
    __shared__ int cntl[512], sm[512], fill[512];
    int b = blockIdx.x, t = threadIdx.x;
    int n = min(gtail[b], BKT_CAP);
    int base = bbase[b];
    cntl[t] = 0;
    __syncthreads();
    for (int i = t; i < n; i += 512)
        atomicAdd(&cntl[bkt[(size_t)b * BKT_CAP + i] >> 17], 1);
    __syncthreads();
    int v = cntl[t];
    sm[t] = v; __syncthreads();
    for (int s = 1; s < 512; s <<= 1) {
        int add = (t >= s) ? sm[t - s] : 0;
        __syncthreads();
        sm[t] += add;
        __syncthreads();
    }
    int excl = sm[t] - v;
    fill[t] = excl;
    int node = (b << BKT_SH) + t;
    if (node < N_NODES) {
        ptr[node]  = base + excl;
        cnt[node]  = v;
        dinv[node] = rsqrtf((float)(v + 1));   // +1 self-loop
    }
    __syncthreads();
    for (int i = t; i < n; i += 512) {
        unsigned e = bkt[(size_t)b * BKT_CAP + i];
        int c = (int)(e >> 17);
        int p = atomicAdd(&fill[c], 1);        // LDS atomic
        srcs[base + p] = (int)(e & 0x1FFFF);
    }
}

// y = dinv[r] * (x @ M), bf16 into ws. 64 rows/block, 4x4 register tile.
__global__ __launch_bounds__(256) void k_xmz(const int* __restrict__ flag,
                                             const void* __restrict__ x,
                                             const float* __restrict__ M,
                                             const float* __restrict__ dinv,
                                             bf16* __restrict__ y) {
    __shared__ float4 Ms4[F_IN * 16];   // [k*16 + cg]
    __shared__ float4 xs4[32 * 64];     // [k4*64 + (row^(k4&7))]
    int t = threadIdx.x;
    bool isbf = (*flag != 0);
    int r0 = blockIdx.x * 64;

#pragma unroll
    for (int q = 0; q < 8; ++q) {
        int i = q * 256 + t;
        Ms4[i] = ((const float4*)M)[i];
    }
    if (isbf) {
        const unsigned short* xb = (const unsigned short*)x;
#pragma unroll
        for (int q = 0; q < 4; ++q) {
            int idx = q * 256 + t;
            int row = idx >> 4, c8 = idx & 15;
            int rr = min(r0 + row, N_NODES - 1);
            uint4 u = ((const uint4*)(xb + (size_t)rr * F_IN))[c8];
            float4 v0 = make_float4(bflo(u.x), bfhi(u.x), bflo(u.y), bfhi(u.y));
            float4 v1 = make_float4(bflo(u.z), bfhi(u.z), bflo(u.w), bfhi(u.w));
            int k40 = c8 * 2, k41 = c8 * 2 + 1;
            xs4[k40 * 64 + (row ^ (k40 & 7))] = v0;
            xs4[k41 * 64 + (row ^ (k41 & 7))] = v1;
        }
    } else {
        const float* xf = (const float*)x;
#pragma unroll
        for (int q = 0; q < 8; ++q) {
            int idx = q * 256 + t;
            int row = idx >> 5, k4 = idx & 31;
            int rr = min(r0 + row, N_NODES - 1);
            float4 v = ((const float4*)(xf + (size_t)rr * F_IN))[k4];
            xs4[k4 * 64 + (row ^ (k4 & 7))] = v;
        }
    }
    __syncthreads();

    int cg = t & 15;
    int rs = t >> 4;
    float4 a0 = {0,0,0,0}, a1 = {0,0,0,0}, a2 = {0,0,0,0}, a3 = {0,0,0,0};

    for (int k4 = 0; k4 < 32; ++k4) {
        float4 m0 = Ms4[(k4 * 4 + 0) * 16 + cg];
        float4 m1 = Ms4[(k4 * 4 + 1) * 16 + cg];
        float4 m2 = Ms4[(k4 * 4 + 2) * 16 + cg];
        float4 m3 = Ms4[(k4 * 4 + 3) * 16 + cg];
        int sw = k4 & 7;
#pragma unroll
        for (int i = 0; i < 4; ++i) {
            int row = rs * 4 + i;
            float4 xv = xs4[k4 * 64 + (row ^ sw)];
            float4* a = (i == 0) ? &a0 : (i == 1) ? &a1 : (i == 2) ? &a2 : &a3;
            a->x += xv.x * m0.x + xv.y * m1.x + xv.z * m2.x + xv.w * m3.x;
            a->y += xv.x * m0.y + xv.y * m1.y + xv.z * m2.y + xv.w * m3.y;
            a->z += xv.x * m0.z + xv.y * m1.z + xv.z * m2.z + xv.w * m3.z;
            a->w += xv.x * m0.w + xv.y * m1.w + xv.z * m2.w + xv.w * m3.w;
        }
    }

    float4 av[4] = {a0, a1, a2, a3};
#pragma unroll
    for (int i = 0; i < 4; ++i) {
        int row = r0 + rs * 4 + i;
        if (row < N_NODES) {
            float d = dinv[row];
            ushort4 pk;
            pk.x = f2bfu(av[i].x * d); pk.y = f2bfu(av[i].y * d);
            pk.z = f2bfu(av[i].z * d); pk.w = f2bfu(av[i].w * d);
            ((ushort4*)((unsigned short*)y + (size_t)row * F_OUT))[cg] = pk;
        }
    }
}

// pull aggregation: one wave per node, lane = feature, unroll-8 gather pipeline.
// y already carries dinv[src]; out = dinv[node]*(y[node] + sum y[srcs]) + cvec.
__global__ __launch_bounds__(256) void k_agg(const int* __restrict__ flag,
                                             const int* __restrict__ ptr,
                                             const int* __restrict__ cnt,
                                             const int* __restrict__ srcs,
                                             const float* __restrict__ dinv,
                                             const bf16* __restrict__ y,
                                             const float* __restrict__ cvec,
                                             void* __restrict__ out) {
    bool isbf = (*flag != 0);
    int node = (blockIdx.x * 256 + threadIdx.x) >> 6;
    int f = threadIdx.x & 63;
    if (node >= N_NODES) return;
    const unsigned short* yu = (const unsigned short*)y;
    float acc = __uint_as_float((unsigned)yu[(size_t)node * F_OUT + f] << 16);  // self
    int n = cnt[node], start = ptr[node];
    for (int j = 0; j < n; j += 64) {
        int m = min(64, n - j);
        int s = 0;
        if (f < m) s = srcs[start + j + f];
        int k = 0;
        for (; k + 8 <= m; k += 8) {
            float zz[8];
#pragma unroll
            for (int u = 0; u < 8; ++u) {
                int su = __shfl(s, k + u, 64);
                zz[u] = __uint_as_float((unsigned)yu[(size_t)su * F_OUT + f] << 16);
            }
#pragma unroll
            for (int u = 0; u < 8; ++u) acc += zz[u];
        }
        for (; k < m; ++k) {
            int sk = __shfl(s, k, 64);
            acc += __uint_as_float((unsigned)yu[(size_t)sk * F_OUT + f] << 16);
        }
    }
    stf(out, (size_t)node * F_OUT + f, isbf, dinv[node] * acc + cvec[f]);
}

// ===================== fallback (atomic multi-pass) path =====================

__global__ void k_init_deg(float* __restrict__ deg) {
    int i = blockIdx.x * blockDim.x + threadIdx.x;
    if (i < N_NODES) deg[i] = 1.0f;
}
__global__ void k_deg(const int* __restrict__ col, float* __restrict__ deg) {
    int e = blockIdx.x * blockDim.x + threadIdx.x;
    if (e < N_EDGES) atomicAdd(&deg[col[e]], 1.0f);
}
__global__ void k_dinv(float* __restrict__ deg) {
    int i = blockIdx.x * blockDim.x + threadIdx.x;
    if (i < N_NODES) deg[i] = rsqrtf(deg[i]);
}
__global__ __launch_bounds__(256) void k_xm(const int* __restrict__ flag,
                                            const void* __restrict__ x,
                                            const float* __restrict__ M,
                                            void* __restrict__ z) {
    __shared__ float Ms[F_IN * F_OUT];
    int t = threadIdx.x;
    for (int i = t; i < F_IN * F_OUT; i += 256) Ms[i] = M[i];
    __syncthreads();
    bool isbf = (*flag != 0);
    int r = blockIdx.x * 4 + (t >> 6);
    int c = t & 63;
    if (r >= N_NODES) return;
    float s = 0.f;
    if (isbf) {
        const bf16* xr = (const bf16*)x + (size_t)r * F_IN;
#pragma unroll
        for (int k = 0; k < F_IN; ++k) s += __bfloat162float(xr[k]) * Ms[k * F_OUT + c];
    } else {
        const float* xr = (const float*)x + (size_t)r * F_IN;
#pragma unroll
        for (int k = 0; k < F_IN; ++k) s += xr[k] * Ms[k * F_OUT + c];
    }
    stf(z, (size_t)r * F_OUT + c, isbf, s);
}
template <int LOGF>
__global__ __launch_bounds__(256) void k_init_acc(const int* __restrict__ flag,
                                                  const float* __restrict__ dinv,
                                                  const void* __restrict__ z,
                                                  float* __restrict__ acc, int base) {
    bool isbf = (*flag != 0);
    int t = blockIdx.x * 256 + threadIdx.x;
    int i = t >> LOGF, f = t & ((1 << LOGF) - 1);
    if (i >= N_NODES) return;
    float d = dinv[i];
    acc[t] = d * d * ldf(z, (size_t)i * F_OUT + base + f, isbf);
}
template <int LOGF>
__global__ __launch_bounds__(256) void k_scatter(const int* __restrict__ flag,
                                                 const int* __restrict__ ei,
                                                 const float* __restrict__ dinv,
                                                 const void* __restrict__ z,
                                                 float* __restrict__ acc, int base) {
    bool isbf = (*flag != 0);
    long long t = (long long)blockIdx.x * 256 + threadIdx.x;
    int e = (int)(t >> LOGF), f = (int)(t & ((1 << LOGF) - 1));
    if (e >= N_EDGES) return;
    int r = ei[e], c = ei[N_EDGES + e];
    float nm = dinv[r] * dinv[c];
    float v  = nm * ldf(z, (size_t)r * F_OUT + base + f, isbf);
    atomicAdd(&acc[((size_t)c << LOGF) + f], v);
}
template <int LOGF>
__global__ __launch_bounds__(256) void k_final(const int* __restrict__ flag,
                                               const float* __restrict__ acc,
                                               const float* __restrict__ cvec,
                                               void* __restrict__ out, int base) {
    bool isbf = (*flag != 0);
    int t = blockIdx.x * 256 + threadIdx.x;
    int i = t >> LOGF, f = t & ((1 << LOGF) - 1);
    if (i >= N_NODES) return;
    stf(out, (size_t)i * F_OUT + base + f, isbf, acc[t] + cvec[base + f]);
}
template <int LOGF>
static void run_passes(const int* flag, const int* ei, const float* dinv,
                       const void* z, float* acc, const float* cvec, void* out,
                       hipStream_t stream) {
    const int fpp = 1 << LOGF;
    const long long tn = (long long)N_NODES * fpp;
    const long long te = (long long)N_EDGES * fpp;
    const int gn = (int)((tn + 255) / 256);
    const int ge = (int)((te + 255) / 256);
    for (int base = 0; base < F_OUT; base += fpp) {
        k_init_acc<LOGF><<<gn, 256, 0, stream>>>(flag, dinv, z, acc, base);
        k_scatter<LOGF><<<ge, 256, 0, stream>>>(flag, ei, dinv, z, acc, base);
        k_final<LOGF><<<gn, 256, 0, stream>>>(flag, acc, cvec, out, base);
    }
}

extern "C" void kernel_launch(void* const* d_in, const int* in_sizes, int n_in,
                              void* d_out, int out_size, void* d_ws, size_t ws_size,
                              hipStream_t stream) {
    const void* x   = d_in[0];
    const int*  ei  = (const int*)d_in[1];
    const void* Wg  = d_in[2];
    const void* bg  = d_in[3];
    const void* Wf  = d_in[4];
    const void* bfc = d_in[5];
    char* ws = (char*)d_ws;

    const size_t CSR_NEED = 20838400;
    if (ws_size >= CSR_NEED) {
        int*      flag  = (int*)(ws + 0);
        float*    dinv  = (float*)(ws + 256);
        float*    M     = (float*)(ws + 400384);
        float*    cvec  = (float*)(ws + 433152);
        int*      cnt   = (int*)(ws + 433664);
        int*      ptr   = (int*)(ws + 833664);
        int*      gtail = (int*)(ws + 1233664);
        int*      bbase = (int*)(ws + 1234560);
        int*      srcs  = (int*)(ws + 1238528);
        bf16*     y     = (bf16*)(ws + 8038400);
        unsigned* bkt   = (unsigned*)(ws + 8038400);   // aliases y; dead before k_xmz

        k_detect<<<1, 64, 0, stream>>>((const unsigned short*)x, flag);
        k_zero<<<1, 256, 0, stream>>>(gtail);
        k_weights<<<(F_IN * F_OUT) / 256, 256, 0, stream>>>(flag, Wg, bg, Wf, bfc, M, cvec);
        k_binA<<<(N_EDGES + EPB_A - 1) / EPB_A, 256, 0, stream>>>(ei, gtail, bkt);
        k_bktscan<<<1, 256, 0, stream>>>(gtail, bbase);
        k_build<<<NB_BKT, 512, 0, stream>>>(bkt, gtail, bbase, ptr, cnt, dinv, srcs);
        k_xmz<<<(N_NODES + 63) / 64, 256, 0, stream>>>(flag, x, M, dinv, y);
        k_agg<<<(N_NODES * 64) / 256, 256, 0, stream>>>(flag, ptr, cnt, srcs, dinv, y, cvec, d_out);
    } else {
        int*   flag = (int*)(ws + 0);
        float* deg  = (float*)(ws + 256);
        float* M    = (float*)(ws + 400384);
        float* cvec = (float*)(ws + 433152);
        float* acc  = (float*)(ws + 433664);

        k_detect<<<1, 64, 0, stream>>>((const unsigned short*)x, flag);
        k_init_deg<<<NBLK, 256, 0, stream>>>(deg);
        k_deg<<<N_EDGES / 256, 256, 0, stream>>>(ei + N_EDGES, deg);
        k_dinv<<<NBLK, 256, 0, stream>>>(deg);
        k_weights<<<(F_IN * F_OUT) / 256, 256, 0, stream>>>(flag, Wg, bg, Wf, bfc, M, cvec);
        k_xm<<<N_NODES / 4, 256, 0, stream>>>(flag, x, M, d_out);
        const size_t bn = 433664;
        if      (ws_size >= bn + (400000ull << 6)) run_passes<6>(flag, ei, deg, d_out, acc, cvec, d_out, stream);
        else if (ws_size >= bn + (400000ull << 5)) run_passes<5>(flag, ei, deg, d_out, acc, cvec, d_out, stream);
        else if (ws_size >= bn + (400000ull << 4)) run_passes<4>(flag, ei, deg, d_out, acc, cvec, d_out, stream);
        else if (ws_size >= bn + (400000ull << 3)) run_passes<3>(flag, ei, deg, d_out, acc, cvec, d_out, stream);
        else if (ws_size >= bn + (400000ull << 2)) run_passes<2>(flag, ei, deg, d_out, acc, cvec, d_out, stream);
        else if (ws_size >= bn + (400000ull << 1)) run_passes<1>(flag, ei, deg, d_out, acc, cvec, d_out, stream);
        else                                       run_passes<0>(flag, ei, deg, d_out, acc, cvec, d_out, stream);
    }
}

// Round 10
// 247.606 us; speedup vs baseline: 3.6726x; 1.0306x over previous
//
#include <hip/hip_runtime.h>
#include <hip/hip_bf16.h>

typedef __hip_bfloat16 bf16;

#define N_NODES 100000
#define N_EDGES 1600000
#define F_IN    128
#define F_OUT   64
#define NBLK    391   // ceil(100000/256)

#define NB_BKT   196    // buckets of 512 target-nodes (c>>9)
#define BKT_SH   9
#define BKT_CAP  8960   // expected 8163/bucket, +8.8 sigma
#define LBIN_CAP 56     // per-block LDS bin cap (expected 20.9, +7.7 sigma)
#define EPB_A    4096   // edges per block, phase A

// ---------------- CSR-path workspace layout (bytes) ----------------
// flag @0 (256) | dinv f32 @256 | M @400,384 | cvec @433,152
// cnt @433,664 | ptr @833,664 | gtail @1,233,664 (784B) | bbase @1,234,560
// srcs int @1,238,528 (6.4MB, ends 7,638,528)
// y bf16 @8,038,400 (12.8MB, ends 20,838,400)  [y = dinv[r]*(x@M)]
// bkt u32 @8,038,400 (7.02MB) ALIASES y: bkt dead before k_xmz writes y.
// total 20,838,400 B. Fallback (atomic multi-pass) path used if ws smaller.

__device__ __forceinline__ float ldf(const void* p, size_t i, bool isbf) {
    return isbf ? __bfloat162float(((const bf16*)p)[i]) : ((const float*)p)[i];
}
__device__ __forceinline__ void stf(void* p, size_t i, bool isbf, float v) {
    if (isbf) ((bf16*)p)[i] = __float2bfloat16(v);
    else      ((float*)p)[i] = v;
}
__device__ __forceinline__ unsigned short f2bfu(float f) {
    __hip_bfloat16 h = __float2bfloat16(f);
    union { __hip_bfloat16 h; unsigned short u; } c; c.h = h; return c.u;
}
__device__ __forceinline__ float bflo(unsigned int u) { return __uint_as_float(u << 16); }
__device__ __forceinline__ float bfhi(unsigned int u) { return __uint_as_float(u & 0xffff0000u); }

// dtype sniff (bf16 vs fp32 world), 64-lane parallel + ballot reduce.
__global__ void k_detect(const unsigned short* __restrict__ w, int* __restrict__ flag) {
    int l = threadIdx.x;
    int good = 0;
#pragma unroll
    for (int q = 0; q < 2; ++q) {
        unsigned short v = w[2 * (l + 64 * q)];
        int e = (v >> 7) & 0xFF;
        if ((e >= 100 && e <= 140) || ((v & 0x7FFF) == 0)) good++;
    }
    unsigned long long m1 = __ballot(good >= 1), m2 = __ballot(good >= 2);
    if (l == 0) *flag = (__popcll(m1) + __popcll(m2) >= 96) ? 1 : 0;
}

// M = W_gcn @ W_fc^T (128x64), cvec = W_fc @ b_gcn + b_fc
__global__ void k_weights(const int* __restrict__ flag,
                          const void* __restrict__ Wg, const void* __restrict__ bg,
                          const void* __restrict__ Wf, const void* __restrict__ bfc,
                          float* __restrict__ M, float* __restrict__ cvec) {
    bool isbf = (*flag != 0);
    int t = blockIdx.x * blockDim.x + threadIdx.x;
    if (t >= F_IN * F_OUT) return;
    int k = t >> 6, c = t & 63;
    float s = 0.f;
    for (int j = 0; j < F_IN; ++j)
        s += ldf(Wg, k * F_IN + j, isbf) * ldf(Wf, c * F_IN + j, isbf);
    M[k * F_OUT + c] = s;
    if (k == 0) {
        float cs = ldf(bfc, c, isbf);
        for (int j = 0; j < F_IN; ++j)
            cs += ldf(bg, j, isbf) * ldf(Wf, c * F_IN + j, isbf);
        cvec[c] = cs;
    }
}

// ===================== CSR (atomic-free) path =====================

__global__ void k_zero(int* __restrict__ gtail) {
    int i = threadIdx.x;
    if (i < NB_BKT) gtail[i] = 0;
}

// phase A: bucketize edges by target>>9 with LDS binning, coalesced flush.
// entry = src (17b) | (c & 511) << 17
__global__ __launch_bounds__(256) void k_binA(const int* __restrict__ ei,
                                              int* __restrict__ gtail,
                                              unsigned* __restrict__ bkt) {
    __shared__ unsigned lbin[NB_BKT * LBIN_CAP];
    __shared__ int lcnt[NB_BKT];
    __shared__ int lbase[NB_BKT];
    int t = threadIdx.x;
    for (int b = t; b < NB_BKT; b += 256) lcnt[b] = 0;
    __syncthreads();
    int e0 = blockIdx.x * EPB_A;
#pragma unroll
    for (int q = 0; q < EPB_A / 256; ++q) {
        int e = e0 + q * 256 + t;
        if (e < N_EDGES) {
            int r = ei[e], c = ei[N_EDGES + e];
            int b = c >> BKT_SH;
            unsigned val = (unsigned)r | ((unsigned)(c & ((1 << BKT_SH) - 1)) << 17);
            int p = atomicAdd(&lcnt[b], 1);
            if (p < LBIN_CAP) {
                lbin[b * LBIN_CAP + p] = val;
            } else {                          // rare overflow: direct global
                int gp = atomicAdd(&gtail[b], 1);
                if (gp < BKT_CAP) bkt[(size_t)b * BKT_CAP + gp] = val;
            }
        }
    }
    __syncthreads();
    for (int b = t; b < NB_BKT; b += 256) {
        int n = min(lcnt[b], LBIN_CAP);
        lbase[b] = atomicAdd(&gtail[b], n);
    }
    __syncthreads();
    for (int idx = t; idx < NB_BKT * LBIN_CAP; idx += 256) {
        int b = idx / LBIN_CAP, i = idx - b * LBIN_CAP;
        if (i < min(lcnt[b], LBIN_CAP)) {
            int gp = lbase[b] + i;
            if (gp < BKT_CAP) bkt[(size_t)b * BKT_CAP + gp] = lbin[idx];
        }
    }
}

// exclusive scan of per-bucket totals -> bucket base offsets in srcs
__global__ void k_bktscan(const int* __restrict__ gtail, int* __restrict__ bbase) {
    __shared__ int sm[256];
    int t = threadIdx.x;
    int v = (t < NB_BKT) ? min(gtail[t], BKT_CAP) : 0;
    sm[t] = v; __syncthreads();
    for (int s = 1; s < 256; s <<= 1) {
        int add = (t >= s) ? sm[t - s] : 0;
        __syncthreads();
        sm[t] += add;
        __syncthreads();
    }
    if (t < NB_BKT) bbase[t] = sm[t] - v;
}

// per-bucket: LDS histogram -> LDS scan -> ptr/cnt/dinv -> place srcs.
__global__ __launch_bounds__(512) void k_build(const unsigned* __restrict__ bkt,
                                               const int* __restrict__ gtail,
                                               const int* __restrict__ bbase,
                                               int* __restrict__ ptr,
                                               int* __restrict__ cnt,
                                               float* __restrict__ dinv,
                                               int* __restrict__ srcs) {
    __shared__ int cntl[512], sm[512], fill[512];
    int b = blockIdx.x, t = threadIdx.x;
    int n = min(gtail[b], BKT_CAP);
    int base = bbase[b];
    cntl[t] = 0;
    __syncthreads();
    for (int i = t; i < n; i += 512)
        atomicAdd(&cntl[bkt[(size_t)b * BKT_CAP + i] >> 17], 1);
    __syncthreads();
    int v = cntl[t];
    sm[t] = v; __syncthreads();
    for (int s = 1; s < 512; s <<= 1) {
        int add = (t >= s) ? sm[t - s] : 0;
        __syncthreads();
        sm[t] += add;
        __syncthreads();
    }
    int excl = sm[t] - v;
    fill[t] = excl;
    int node = (b << BKT_SH) + t;
    if (node < N_NODES) {
        ptr[node]  = base + excl;
        cnt[node]  = v;
        dinv[node] = rsqrtf((float)(v + 1));   // +1 self-loop
    }
    __syncthreads();
    for (int i = t; i < n; i += 512) {
        unsigned e = bkt[(size_t)b * BKT_CAP + i];
        int c = (int)(e >> 17);
        int p = atomicAdd(&fill[c], 1);        // LDS atomic
        srcs[base + p] = (int)(e & 0x1FFFF);
    }
}

// y = dinv[r] * (x @ M), bf16 into ws. 64 rows/block, 4x4 register tile.
__global__ __launch_bounds__(256) void k_xmz(const int* __restrict__ flag,
                                             const void* __restrict__ x,
                                             const float* __restrict__ M,
                                             const float* __restrict__ dinv,
                                             bf16* __restrict__ y) {
    __shared__ float4 Ms4[F_IN * 16];   // [k*16 + cg]
    __shared__ float4 xs4[32 * 64];     // [k4*64 + (row^(k4&7))]
    int t = threadIdx.x;
    bool isbf = (*flag != 0);
    int r0 = blockIdx.x * 64;

#pragma unroll
    for (int q = 0; q < 8; ++q) {
        int i = q * 256 + t;
        Ms4[i] = ((const float4*)M)[i];
    }
    if (isbf) {
        const unsigned short* xb = (const unsigned short*)x;
#pragma unroll
        for (int q = 0; q < 4; ++q) {
            int idx = q * 256 + t;
            int row = idx >> 4, c8 = idx & 15;
            int rr = min(r0 + row, N_NODES - 1);
            uint4 u = ((const uint4*)(xb + (size_t)rr * F_IN))[c8];
            float4 v0 = make_float4(bflo(u.x), bfhi(u.x), bflo(u.y), bfhi(u.y));
            float4 v1 = make_float4(bflo(u.z), bfhi(u.z), bflo(u.w), bfhi(u.w));
            int k40 = c8 * 2, k41 = c8 * 2 + 1;
            xs4[k40 * 64 + (row ^ (k40 & 7))] = v0;
            xs4[k41 * 64 + (row ^ (k41 & 7))] = v1;
        }
    } else {
        const float* xf = (const float*)x;
#pragma unroll
        for (int q = 0; q < 8; ++q) {
            int idx = q * 256 + t;
            int row = idx >> 5, k4 = idx & 31;
            int rr = min(r0 + row, N_NODES - 1);
            float4 v = ((const float4*)(xf + (size_t)rr * F_IN))[k4];
            xs4[k4 * 64 + (row ^ (k4 & 7))] = v;
        }
    }
    __syncthreads();

    int cg = t & 15;
    int rs = t >> 4;
    float4 a0 = {0,0,0,0}, a1 = {0,0,0,0}, a2 = {0,0,0,0}, a3 = {0,0,0,0};

    for (int k4 = 0; k4 < 32; ++k4) {
        float4 m0 = Ms4[(k4 * 4 + 0) * 16 + cg];
        float4 m1 = Ms4[(k4 * 4 + 1) * 16 + cg];
        float4 m2 = Ms4[(k4 * 4 + 2) * 16 + cg];
        float4 m3 = Ms4[(k4 * 4 + 3) * 16 + cg];
        int sw = k4 & 7;
#pragma unroll
        for (int i = 0; i < 4; ++i) {
            int row = rs * 4 + i;
            float4 xv = xs4[k4 * 64 + (row ^ sw)];
            float4* a = (i == 0) ? &a0 : (i == 1) ? &a1 : (i == 2) ? &a2 : &a3;
            a->x += xv.x * m0.x + xv.y * m1.x + xv.z * m2.x + xv.w * m3.x;
            a->y += xv.x * m0.y + xv.y * m1.y + xv.z * m2.y + xv.w * m3.y;
            a->z += xv.x * m0.z + xv.y * m1.z + xv.z * m2.z + xv.w * m3.z;
            a->w += xv.x * m0.w + xv.y * m1.w + xv.z * m2.w + xv.w * m3.w;
        }
    }

    float4 av[4] = {a0, a1, a2, a3};
#pragma unroll
    for (int i = 0; i < 4; ++i) {
        int row = r0 + rs * 4 + i;
        if (row < N_NODES) {
            float d = dinv[row];
            ushort4 pk;
            pk.x = f2bfu(av[i].x * d); pk.y = f2bfu(av[i].y * d);
            pk.z = f2bfu(av[i].z * d); pk.w = f2bfu(av[i].w * d);
            ((ushort4*)((unsigned short*)y + (size_t)row * F_OUT))[cg] = pk;
        }
    }
}

// pull aggregation v3: one wave per node. Lane l: edge-slot g=l>>3,
// feature-octet j8=l&7. One wave-gather = 8 edges x uint4 (8 bf16 feats)
// = 1KB coalesced. Butterfly-reduce over g, lanes 0..7 finalize.
__global__ __launch_bounds__(256) void k_agg(const int* __restrict__ flag,
                                             const int* __restrict__ ptr,
                                             const int* __restrict__ cnt,
                                             const int* __restrict__ srcs,
                                             const float* __restrict__ dinv,
                                             const bf16* __restrict__ y,
                                             const float* __restrict__ cvec,
                                             void* __restrict__ out) {
    int node = (blockIdx.x * 256 + threadIdx.x) >> 6;
    int lane = threadIdx.x & 63;
    if (node >= N_NODES) return;
    int g  = lane >> 3;   // edge slot within pass
    int j8 = lane & 7;    // feature octet
    const uint4* y4 = (const uint4*)y;   // one y row = 8 uint4

    float acc[8];
#pragma unroll
    for (int i = 0; i < 8; ++i) acc[i] = 0.f;

    int n = cnt[node], start = ptr[node];
    for (int j = 0; j < n; j += 64) {
        int m = min(64, n - j);
        int s = 0;
        if (lane < m) s = srcs[start + j + lane];
#pragma unroll
        for (int pass = 0; pass < 8; ++pass) {
            int eidx = pass * 8 + g;
            int su = __shfl(s, pass * 8 + g, 64);
            if (eidx < m) {
                uint4 v = y4[(size_t)su * 8 + j8];
                acc[0] += bflo(v.x); acc[1] += bfhi(v.x);
                acc[2] += bflo(v.y); acc[3] += bfhi(v.y);
                acc[4] += bflo(v.z); acc[5] += bfhi(v.z);
                acc[6] += bflo(v.w); acc[7] += bfhi(v.w);
            }
            if (pass * 8 + 8 >= m) break;
        }
    }

    // reduce over edge-slot groups (xor lane bits 3,4,5)
#pragma unroll
    for (int d = 8; d < 64; d <<= 1) {
#pragma unroll
        for (int i = 0; i < 8; ++i)
            acc[i] += __shfl_xor(acc[i], d, 64);
    }

    if (g == 0) {   // lanes 0..7 finalize feature octets
        bool isbf = (*flag != 0);
        uint4 sv = y4[(size_t)node * 8 + j8];   // self-loop row
        float sl[8] = { bflo(sv.x), bfhi(sv.x), bflo(sv.y), bfhi(sv.y),
                        bflo(sv.z), bfhi(sv.z), bflo(sv.w), bfhi(sv.w) };
        float dn = dinv[node];
        size_t ob = (size_t)node * F_OUT + j8 * 8;
        if (isbf) {
            ushort4 p0, p1;
            p0.x = f2bfu(dn * (acc[0] + sl[0]) + cvec[j8 * 8 + 0]);
            p0.y = f2bfu(dn * (acc[1] + sl[1]) + cvec[j8 * 8 + 1]);
            p0.z = f2bfu(dn * (acc[2] + sl[2]) + cvec[j8 * 8 + 2]);
            p0.w = f2bfu(dn * (acc[3] + sl[3]) + cvec[j8 * 8 + 3]);
            p1.x = f2bfu(dn * (acc[4] + sl[4]) + cvec[j8 * 8 + 4]);
            p1.y = f2bfu(dn * (acc[5] + sl[5]) + cvec[j8 * 8 + 5]);
            p1.z = f2bfu(dn * (acc[6] + sl[6]) + cvec[j8 * 8 + 6]);
            p1.w = f2bfu(dn * (acc[7] + sl[7]) + cvec[j8 * 8 + 7]);
            ushort4* ob4 = (ushort4*)((unsigned short*)out + ob);
            ob4[0] = p0; ob4[1] = p1;
        } else {
            float4 q0, q1;
            q0.x = dn * (acc[0] + sl[0]) + cvec[j8 * 8 + 0];
            q0.y = dn * (acc[1] + sl[1]) + cvec[j8 * 8 + 1];
            q0.z = dn * (acc[2] + sl[2]) + cvec[j8 * 8 + 2];
            q0.w = dn * (acc[3] + sl[3]) + cvec[j8 * 8 + 3];
            q1.x = dn * (acc[4] + sl[4]) + cvec[j8 * 8 + 4];
            q1.y = dn * (acc[5] + sl[5]) + cvec[j8 * 8 + 5];
            q1.z = dn * (acc[6] + sl[6]) + cvec[j8 * 8 + 6];
            q1.w = dn * (acc[7] + sl[7]) + cvec[j8 * 8 + 7];
            float4* of4 = (float4*)((float*)out + ob);
            of4[0] = q0; of4[1] = q1;
        }
    }
}

// ===================== fallback (atomic multi-pass) path =====================

__global__ void k_init_deg(float* __restrict__ deg) {
    int i = blockIdx.x * blockDim.x + threadIdx.x;
    if (i < N_NODES) deg[i] = 1.0f;
}
__global__ void k_deg(const int* __restrict__ col, float* __restrict__ deg) {
    int e = blockIdx.x * blockDim.x + threadIdx.x;
    if (e < N_EDGES) atomicAdd(&deg[col[e]], 1.0f);
}
__global__ void k_dinv(float* __restrict__ deg) {
    int i = blockIdx.x * blockDim.x + threadIdx.x;
    if (i < N_NODES) deg[i] = rsqrtf(deg[i]);
}
__global__ __launch_bounds__(256) void k_xm(const int* __restrict__ flag,
                                            const void* __restrict__ x,
                                            const float* __restrict__ M,
                                            void* __restrict__ z) {
    __shared__ float Ms[F_IN * F_OUT];
    int t = threadIdx.x;
    for (int i = t; i < F_IN * F_OUT; i += 256) Ms[i] = M[i];
    __syncthreads();
    bool isbf = (*flag != 0);
    int r = blockIdx.x * 4 + (t >> 6);
    int c = t & 63;
    if (r >= N_NODES) return;
    float s = 0.f;
    if (isbf) {
        const bf16* xr = (const bf16*)x + (size_t)r * F_IN;
#pragma unroll
        for (int k = 0; k < F_IN; ++k) s += __bfloat162float(xr[k]) * Ms[k * F_OUT + c];
    } else {
        const float* xr = (const float*)x + (size_t)r * F_IN;
#pragma unroll
        for (int k = 0; k < F_IN; ++k) s += xr[k] * Ms[k * F_OUT + c];
    }
    stf(z, (size_t)r * F_OUT + c, isbf, s);
}
template <int LOGF>
__global__ __launch_bounds__(256) void k_init_acc(const int* __restrict__ flag,
                                                  const float* __restrict__ dinv,
                                                  const void* __restrict__ z,
                                                  float* __restrict__ acc, int base) {
    bool isbf = (*flag != 0);
    int t = blockIdx.x * 256 + threadIdx.x;
    int i = t >> LOGF, f = t & ((1 << LOGF) - 1);
    if (i >= N_NODES) return;
    float d = dinv[i];
    acc[t] = d * d * ldf(z, (size_t)i * F_OUT + base + f, isbf);
}
template <int LOGF>
__global__ __launch_bounds__(256) void k_scatter(const int* __restrict__ flag,
                                                 const int* __restrict__ ei,
                                                 const float* __restrict__ dinv,
                                                 const void* __restrict__ z,
                                                 float* __restrict__ acc, int base) {
    bool isbf = (*flag != 0);
    long long t = (long long)blockIdx.x * 256 + threadIdx.x;
    int e = (int)(t >> LOGF), f = (int)(t & ((1 << LOGF) - 1));
    if (e >= N_EDGES) return;
    int r = ei[e], c = ei[N_EDGES + e];
    float nm = dinv[r] * dinv[c];
    float v  = nm * ldf(z, (size_t)r * F_OUT + base + f, isbf);
    atomicAdd(&acc[((size_t)c << LOGF) + f], v);
}
template <int LOGF>
__global__ __launch_bounds__(256) void k_final(const int* __restrict__ flag,
                                               const float* __restrict__ acc,
                                               const float* __restrict__ cvec,
                                               void* __restrict__ out, int base) {
    bool isbf = (*flag != 0);
    int t = blockIdx.x * 256 + threadIdx.x;
    int i = t >> LOGF, f = t & ((1 << LOGF) - 1);
    if (i >= N_NODES) return;
    stf(out, (size_t)i * F_OUT + base + f, isbf, acc[t] + cvec[base + f]);
}
template <int LOGF>
static void run_passes(const int* flag, const int* ei, const float* dinv,
                       const void* z, float* acc, const float* cvec, void* out,
                       hipStream_t stream) {
    const int fpp = 1 << LOGF;
    const long long tn = (long long)N_NODES * fpp;
    const long long te = (long long)N_EDGES * fpp;
    const int gn = (int)((tn + 255) / 256);
    const int ge = (int)((te + 255) / 256);
    for (int base = 0; base < F_OUT; base += fpp) {
        k_init_acc<LOGF><<<gn, 256, 0, stream>>>(flag, dinv, z, acc, base);
        k_scatter<LOGF><<<ge, 256, 0, stream>>>(flag, ei, dinv, z, acc, base);
        k_final<LOGF><<<gn, 256, 0, stream>>>(flag, acc, cvec, out, base);
    }
}

extern "C" void kernel_launch(void* const* d_in, const int* in_sizes, int n_in,
                              void* d_out, int out_size, void* d_ws, size_t ws_size,
                              hipStream_t stream) {
    const void* x   = d_in[0];
    const int*  ei  = (const int*)d_in[1];
    const void* Wg  = d_in[2];
    const void* bg  = d_in[3];
    const void* Wf  = d_in[4];
    const void* bfc = d_in[5];
    char* ws = (char*)d_ws;

    const size_t CSR_NEED = 20838400;
    if (ws_size >= CSR_NEED) {
        int*      flag  = (int*)(ws + 0);
        float*    dinv  = (float*)(ws + 256);
        float*    M     = (float*)(ws + 400384);
        float*    cvec  = (float*)(ws + 433152);
        int*      cnt   = (int*)(ws + 433664);
        int*      ptr   = (int*)(ws + 833664);
        int*      gtail = (int*)(ws + 1233664);
        int*      bbase = (int*)(ws + 1234560);
        int*      srcs  = (int*)(ws + 1238528);
        bf16*     y     = (bf16*)(ws + 8038400);
        unsigned* bkt   = (unsigned*)(ws + 8038400);   // aliases y; dead before k_xmz

        k_detect<<<1, 64, 0, stream>>>((const unsigned short*)x, flag);
        k_zero<<<1, 256, 0, stream>>>(gtail);
        k_weights<<<(F_IN * F_OUT) / 256, 256, 0, stream>>>(flag, Wg, bg, Wf, bfc, M, cvec);
        k_binA<<<(N_EDGES + EPB_A - 1) / EPB_A, 256, 0, stream>>>(ei, gtail, bkt);
        k_bktscan<<<1, 256, 0, stream>>>(gtail, bbase);
        k_build<<<NB_BKT, 512, 0, stream>>>(bkt, gtail, bbase, ptr, cnt, dinv, srcs);
        k_xmz<<<(N_NODES + 63) / 64, 256, 0, stream>>>(flag, x, M, dinv, y);
        k_agg<<<(N_NODES * 64) / 256, 256, 0, stream>>>(flag, ptr, cnt, srcs, dinv, y, cvec, d_out);
    } else {
        int*   flag = (int*)(ws + 0);
        float* deg  = (float*)(ws + 256);
        float* M    = (float*)(ws + 400384);
        float* cvec = (float*)(ws + 433152);
        float* acc  = (float*)(ws + 433664);

        k_detect<<<1, 64, 0, stream>>>((const unsigned short*)x, flag);
        k_init_deg<<<NBLK, 256, 0, stream>>>(deg);
        k_deg<<<N_EDGES / 256, 256, 0, stream>>>(ei + N_EDGES, deg);
        k_dinv<<<NBLK, 256, 0, stream>>>(deg);
        k_weights<<<(F_IN * F_OUT) / 256, 256, 0, stream>>>(flag, Wg, bg, Wf, bfc, M, cvec);
        k_xm<<<N_NODES / 4, 256, 0, stream>>>(flag, x, M, d_out);
        const size_t bn = 433664;
        if      (ws_size >= bn + (400000ull << 6)) run_passes<6>(flag, ei, deg, d_out, acc, cvec, d_out, stream);
        else if (ws_size >= bn + (400000ull << 5)) run_passes<5>(flag, ei, deg, d_out, acc, cvec, d_out, stream);
        else if (ws_size >= bn + (400000ull << 4)) run_passes<4>(flag, ei, deg, d_out, acc, cvec, d_out, stream);
        else if (ws_size >= bn + (400000ull << 3)) run_passes<3>(flag, ei, deg, d_out, acc, cvec, d_out, stream);
        else if (ws_size >= bn + (400000ull << 2)) run_passes<2>(flag, ei, deg, d_out, acc, cvec, d_out, stream);
        else if (ws_size >= bn + (400000ull << 1)) run_passes<1>(flag, ei, deg, d_out, acc, cvec, d_out, stream);
        else                                       run_passes<0>(flag, ei, deg, d_out, acc, cvec, d_out, stream);
    }
}

// Round 11
// 233.926 us; speedup vs baseline: 3.8873x; 1.0585x over previous
//
#include <hip/hip_runtime.h>
#include <hip/hip_bf16.h>

typedef __hip_bfloat16 bf16;

#define N_NODES 100000
#define N_EDGES 1600000
#define F_IN    128
#define F_OUT   64
#define NBLK    391   // ceil(100000/256)

#define NB_BKT   196    // buckets of 512 target-nodes (c>>9)
#define BKT_SH   9
#define BKT_CAP  8960   // expected 8163/bucket, +8.8 sigma
#define LBIN_CAP 56     // per-block LDS bin cap (expected 20.9, +7.7 sigma)
#define EPB_A    4096   // edges per block, phase A

// ---------------- CSR-path workspace layout (bytes) ----------------
// flag @0 (256) | dinv f32 @256 | M @400,384 | cvec @433,152
// cnt @433,664 | ptr @833,664 | gtail @1,233,664 (784B) | bbase @1,234,560
// srcs int @1,238,528 (6.4MB, ends 7,638,528)
// y bf16 @8,038,400 (12.8MB, ends 20,838,400)  [y = dinv[r]*(x@M)]
// bkt u32 @8,038,400 (7.02MB) ALIASES y: bkt dead before k_xmz writes y.
// total 20,838,400 B. Fallback (atomic multi-pass) path used if ws smaller.

__device__ __forceinline__ float ldf(const void* p, size_t i, bool isbf) {
    return isbf ? __bfloat162float(((const bf16*)p)[i]) : ((const float*)p)[i];
}
__device__ __forceinline__ void stf(void* p, size_t i, bool isbf, float v) {
    if (isbf) ((bf16*)p)[i] = __float2bfloat16(v);
    else      ((float*)p)[i] = v;
}
__device__ __forceinline__ unsigned short f2bfu(float f) {
    __hip_bfloat16 h = __float2bfloat16(f);
    union { __hip_bfloat16 h; unsigned short u; } c; c.h = h; return c.u;
}
__device__ __forceinline__ float bflo(unsigned int u) { return __uint_as_float(u << 16); }
__device__ __forceinline__ float bfhi(unsigned int u) { return __uint_as_float(u & 0xffff0000u); }

// dtype sniff (bf16 vs fp32 world), 64-lane parallel + ballot reduce.
__global__ void k_detect(const unsigned short* __restrict__ w, int* __restrict__ flag) {
    int l = threadIdx.x;
    int good = 0;
#pragma unroll
    for (int q = 0; q < 2; ++q) {
        unsigned short v = w[2 * (l + 64 * q)];
        int e = (v >> 7) & 0xFF;
        if ((e >= 100 && e <= 140) || ((v & 0x7FFF) == 0)) good++;
    }
    unsigned long long m1 = __ballot(good >= 1), m2 = __ballot(good >= 2);
    if (l == 0) *flag = (__popcll(m1) + __popcll(m2) >= 96) ? 1 : 0;
}

// M = W_gcn @ W_fc^T (128x64), cvec = W_fc @ b_gcn + b_fc
__global__ void k_weights(const int* __restrict__ flag,
                          const void* __restrict__ Wg, const void* __restrict__ bg,
                          const void* __restrict__ Wf, const void* __restrict__ bfc,
                          float* __restrict__ M, float* __restrict__ cvec) {
    bool isbf = (*flag != 0);
    int t = blockIdx.x * blockDim.x + threadIdx.x;
    if (t >= F_IN * F_OUT) return;
    int k = t >> 6, c = t & 63;
    float s = 0.f;
    for (int j = 0; j < F_IN; ++j)
        s += ldf(Wg, k * F_IN + j, isbf) * ldf(Wf, c * F_IN + j, isbf);
    M[k * F_OUT + c] = s;
    if (k == 0) {
        float cs = ldf(bfc, c, isbf);
        for (int j = 0; j < F_IN; ++j)
            cs += ldf(bg, j, isbf) * ldf(Wf, c * F_IN + j, isbf);
        cvec[c] = cs;
    }
}

// ===================== CSR (atomic-free) path =====================

__global__ void k_zero(int* __restrict__ gtail) {
    int i = threadIdx.x;
    if (i < NB_BKT) gtail[i] = 0;
}

// phase A: bucketize edges by target>>9 with LDS binning, coalesced flush.
// entry = src (17b) | (c & 511) << 17
__global__ __launch_bounds__(256) void k_binA(const int* __restrict__ ei,
                                              int* __restrict__ gtail,
                                              unsigned* __restrict__ bkt) {
    __shared__ unsigned lbin[NB_BKT * LBIN_CAP];
    __shared__ int lcnt[NB_BKT];
    __shared__ int lbase[NB_BKT];
    int t = threadIdx.x;
    for (int b = t; b < NB_BKT; b += 256) lcnt[b] = 0;
    __syncthreads();
    int e0 = blockIdx.x * EPB_A;
#pragma unroll
    for (int q = 0; q < EPB_A / 256; ++q) {
        int e = e0 + q * 256 + t;
        if (e < N_EDGES) {
            int r = ei[e], c = ei[N_EDGES + e];
            int b = c >> BKT_SH;
            unsigned val = (unsigned)r | ((unsigned)(c & ((1 << BKT_SH) - 1)) << 17);
            int p = atomicAdd(&lcnt[b], 1);
            if (p < LBIN_CAP) {
                lbin[b * LBIN_CAP + p] = val;
            } else {                          // rare overflow: direct global
                int gp = atomicAdd(&gtail[b], 1);
                if (gp < BKT_CAP) bkt[(size_t)b * BKT_CAP + gp] = val;
            }
        }
    }
    __syncthreads();
    for (int b = t; b < NB_BKT; b += 256) {
        int n = min(lcnt[b], LBIN_CAP);
        lbase[b] = atomicAdd(&gtail[b], n);
    }
    __syncthreads();
    // flush: wave w owns bins w, w+4, ... (no integer division)
    int w = t >> 6, l = t & 63;
    for (int b = w; b < NB_BKT; b += 4) {
        int nB = min(lcnt[b], LBIN_CAP);
        int gp0 = lbase[b];
        for (int i = l; i < nB; i += 64) {
            int gp = gp0 + i;
            if (gp < BKT_CAP) bkt[(size_t)b * BKT_CAP + gp] = lbin[b * LBIN_CAP + i];
        }
    }
}

// exclusive scan of per-bucket totals -> bucket base offsets in srcs
__global__ void k_bktscan(const int* __restrict__ gtail, int* __restrict__ bbase) {
    __shared__ int sm[256];
    int t = threadIdx.x;
    int v = (t < NB_BKT) ? min(gtail[t], BKT_CAP) : 0;
    sm[t] = v; __syncthreads();
    for (int s = 1; s < 256; s <<= 1) {
        int add = (t >= s) ? sm[t - s] : 0;
        __syncthreads();
        sm[t] += add;
        __syncthreads();
    }
    if (t < NB_BKT) bbase[t] = sm[t] - v;
}

// per-bucket: LDS histogram -> LDS scan -> ptr/cnt/dinv -> place srcs.
__global__ __launch_bounds__(512) void k_build(const unsigned* __restrict__ bkt,
                                               const int* __restrict__ gtail,
                                               const int* __restrict__ bbase,
                                               int* __restrict__ ptr,
                                               int* __restrict__ cnt,
                                               float* __restrict__ dinv,
                                               int* __restrict__ srcs) {
    __shared__ int cntl[512], sm[512], fill[512];
    int b = blockIdx.x, t = threadIdx.x;
    int n = min(gtail[b], BKT_CAP);
    int base = bbase[b];
    cntl[t] = 0;
    __syncthreads();
    for (int i = t; i < n; i += 512)
        atomicAdd(&cntl[bkt[(size_t)b * BKT_CAP + i] >> 17], 1);
    __syncthreads();
    int v = cntl[t];
    sm[t] = v; __syncthreads();
    for (int s = 1; s < 512; s <<= 1) {
        int add = (t >= s) ? sm[t - s] : 0;
        __syncthreads();
        sm[t] += add;
        __syncthreads();
    }
    int excl = sm[t] - v;
    fill[t] = excl;
    int node = (b << BKT_SH) + t;
    if (node < N_NODES) {
        ptr[node]  = base + excl;
        cnt[node]  = v;
        dinv[node] = rsqrtf((float)(v + 1));   // +1 self-loop
    }
    __syncthreads();
    for (int i = t; i < n; i += 512) {
        unsigned e = bkt[(size_t)b * BKT_CAP + i];
        int c = (int)(e >> 17);
        int p = atomicAdd(&fill[c], 1);        // LDS atomic
        srcs[base + p] = (int)(e & 0x1FFFF);
    }
}

// y = dinv[r] * (x @ M), bf16 into ws. 64 rows/block, 4x4 register tile.
__global__ __launch_bounds__(256) void k_xmz(const int* __restrict__ flag,
                                             const void* __restrict__ x,
                                             const float* __restrict__ M,
                                             const float* __restrict__ dinv,
                                             bf16* __restrict__ y) {
    __shared__ float4 Ms4[F_IN * 16];   // [k*16 + cg]
    __shared__ float4 xs4[32 * 64];     // [k4*64 + (row^(k4&7))]
    int t = threadIdx.x;
    bool isbf = (*flag != 0);
    int r0 = blockIdx.x * 64;

#pragma unroll
    for (int q = 0; q < 8; ++q) {
        int i = q * 256 + t;
        Ms4[i] = ((const float4*)M)[i];
    }
    if (isbf) {
        const unsigned short* xb = (const unsigned short*)x;
#pragma unroll
        for (int q = 0; q < 4; ++q) {
            int idx = q * 256 + t;
            int row = idx >> 4, c8 = idx & 15;
            int rr = min(r0 + row, N_NODES - 1);
            uint4 u = ((const uint4*)(xb + (size_t)rr * F_IN))[c8];
            float4 v0 = make_float4(bflo(u.x), bfhi(u.x), bflo(u.y), bfhi(u.y));
            float4 v1 = make_float4(bflo(u.z), bfhi(u.z), bflo(u.w), bfhi(u.w));
            int k40 = c8 * 2, k41 = c8 * 2 + 1;
            xs4[k40 * 64 + (row ^ (k40 & 7))] = v0;
            xs4[k41 * 64 + (row ^ (k41 & 7))] = v1;
        }
    } else {
        const float* xf = (const float*)x;
#pragma unroll
        for (int q = 0; q < 8; ++q) {
            int idx = q * 256 + t;
            int row = idx >> 5, k4 = idx & 31;
            int rr = min(r0 + row, N_NODES - 1);
            float4 v = ((const float4*)(xf + (size_t)rr * F_IN))[k4];
            xs4[k4 * 64 + (row ^ (k4 & 7))] = v;
        }
    }
    __syncthreads();

    int cg = t & 15;
    int rs = t >> 4;
    float4 a0 = {0,0,0,0}, a1 = {0,0,0,0}, a2 = {0,0,0,0}, a3 = {0,0,0,0};

    for (int k4 = 0; k4 < 32; ++k4) {
        float4 m0 = Ms4[(k4 * 4 + 0) * 16 + cg];
        float4 m1 = Ms4[(k4 * 4 + 1) * 16 + cg];
        float4 m2 = Ms4[(k4 * 4 + 2) * 16 + cg];
        float4 m3 = Ms4[(k4 * 4 + 3) * 16 + cg];
        int sw = k4 & 7;
#pragma unroll
        for (int i = 0; i < 4; ++i) {
            int row = rs * 4 + i;
            float4 xv = xs4[k4 * 64 + (row ^ sw)];
            float4* a = (i == 0) ? &a0 : (i == 1) ? &a1 : (i == 2) ? &a2 : &a3;
            a->x += xv.x * m0.x + xv.y * m1.x + xv.z * m2.x + xv.w * m3.x;
            a->y += xv.x * m0.y + xv.y * m1.y + xv.z * m2.y + xv.w * m3.y;
            a->z += xv.x * m0.z + xv.y * m1.z + xv.z * m2.z + xv.w * m3.z;
            a->w += xv.x * m0.w + xv.y * m1.w + xv.z * m2.w + xv.w * m3.w;
        }
    }

    float4 av[4] = {a0, a1, a2, a3};
#pragma unroll
    for (int i = 0; i < 4; ++i) {
        int row = r0 + rs * 4 + i;
        if (row < N_NODES) {
            float d = dinv[row];
            ushort4 pk;
            pk.x = f2bfu(av[i].x * d); pk.y = f2bfu(av[i].y * d);
            pk.z = f2bfu(av[i].z * d); pk.w = f2bfu(av[i].w * d);
            ((ushort4*)((unsigned short*)y + (size_t)row * F_OUT))[cg] = pk;
        }
    }
}

// pull aggregation v4: 8 nodes per wave. Lane = (group g = node, octet j8).
// Each group accumulates its own node's 8 feature octets in registers —
// no cross-lane reduction. One wave-gather = 8 nodes x 16B = 1KB coalesced.
__global__ __launch_bounds__(256) void k_agg(const int* __restrict__ flag,
                                             const int* __restrict__ ptr,
                                             const int* __restrict__ cnt,
                                             const int* __restrict__ srcs,
                                             const float* __restrict__ dinv,
                                             const bf16* __restrict__ y,
                                             const float* __restrict__ cvec,
                                             void* __restrict__ out) {
    int wid  = (blockIdx.x * 256 + threadIdx.x) >> 6;
    int lane = threadIdx.x & 63;
    int g  = lane >> 3;          // node slot in wave
    int j8 = lane & 7;           // feature octet
    int node = wid * 8 + g;      // grid sized so node <= 99999 always when wid valid
    bool alive = node < N_NODES;
    int n = 0, start = 0;
    if (alive) { n = cnt[node]; start = ptr[node]; }
    const uint4* y4 = (const uint4*)y;

    float acc[8];
#pragma unroll
    for (int i = 0; i < 8; ++i) acc[i] = 0.f;

    for (int b = 0; __any(b < n); b += 8) {
        int s = 0;
        int idx = b + j8;
        if (idx < n) s = srcs[start + idx];   // lane (g,j8) holds edge b+j8 of node g
#pragma unroll
        for (int k = 0; k < 8; ++k) {
            int su = __shfl(s, (g << 3) | k, 64);
            if (b + k < n) {
                uint4 v = y4[(size_t)su * 8 + j8];
                acc[0] += bflo(v.x); acc[1] += bfhi(v.x);
                acc[2] += bflo(v.y); acc[3] += bfhi(v.y);
                acc[4] += bflo(v.z); acc[5] += bfhi(v.z);
                acc[6] += bflo(v.w); acc[7] += bfhi(v.w);
            }
        }
    }

    if (!alive) return;
    bool isbf = (*flag != 0);
    uint4 sv = y4[(size_t)node * 8 + j8];   // self-loop row
    float dn = dinv[node];
    const float4* cv4 = (const float4*)cvec;
    float4 c0 = cv4[j8 * 2], c1 = cv4[j8 * 2 + 1];
    size_t ob = (size_t)node * F_OUT + j8 * 8;
    if (isbf) {
        ushort4 p0, p1;
        p0.x = f2bfu(dn * (acc[0] + bflo(sv.x)) + c0.x);
        p0.y = f2bfu(dn * (acc[1] + bfhi(sv.x)) + c0.y);
        p0.z = f2bfu(dn * (acc[2] + bflo(sv.y)) + c0.z);
        p0.w = f2bfu(dn * (acc[3] + bfhi(sv.y)) + c0.w);
        p1.x = f2bfu(dn * (acc[4] + bflo(sv.z)) + c1.x);
        p1.y = f2bfu(dn * (acc[5] + bfhi(sv.z)) + c1.y);
        p1.z = f2bfu(dn * (acc[6] + bflo(sv.w)) + c1.z);
        p1.w = f2bfu(dn * (acc[7] + bfhi(sv.w)) + c1.w);
        ushort4* ob4 = (ushort4*)((unsigned short*)out + ob);
        ob4[0] = p0; ob4[1] = p1;
    } else {
        float4 q0, q1;
        q0.x = dn * (acc[0] + bflo(sv.x)) + c0.x;
        q0.y = dn * (acc[1] + bfhi(sv.x)) + c0.y;
        q0.z = dn * (acc[2] + bflo(sv.y)) + c0.z;
        q0.w = dn * (acc[3] + bfhi(sv.y)) + c0.w;
        q1.x = dn * (acc[4] + bflo(sv.z)) + c1.x;
        q1.y = dn * (acc[5] + bfhi(sv.z)) + c1.y;
        q1.z = dn * (acc[6] + bflo(sv.w)) + c1.z;
        q1.w = dn * (acc[7] + bfhi(sv.w)) + c1.w;
        float4* of4 = (float4*)((float*)out + ob);
        of4[0] = q0; of4[1] = q1;
    }
}

// ===================== fallback (atomic multi-pass) path =====================

__global__ void k_init_deg(float* __restrict__ deg) {
    int i = blockIdx.x * blockDim.x + threadIdx.x;
    if (i < N_NODES) deg[i] = 1.0f;
}
__global__ void k_deg(const int* __restrict__ col, float* __restrict__ deg) {
    int e = blockIdx.x * blockDim.x + threadIdx.x;
    if (e < N_EDGES) atomicAdd(&deg[col[e]], 1.0f);
}
__global__ void k_dinv(float* __restrict__ deg) {
    int i = blockIdx.x * blockDim.x + threadIdx.x;
    if (i < N_NODES) deg[i] = rsqrtf(deg[i]);
}
__global__ __launch_bounds__(256) void k_xm(const int* __restrict__ flag,
                                            const void* __restrict__ x,
                                            const float* __restrict__ M,
                                            void* __restrict__ z) {
    __shared__ float Ms[F_IN * F_OUT];
    int t = threadIdx.x;
    for (int i = t; i < F_IN * F_OUT; i += 256) Ms[i] = M[i];
    __syncthreads();
    bool isbf = (*flag != 0);
    int r = blockIdx.x * 4 + (t >> 6);
    int c = t & 63;
    if (r >= N_NODES) return;
    float s = 0.f;
    if (isbf) {
        const bf16* xr = (const bf16*)x + (size_t)r * F_IN;
#pragma unroll
        for (int k = 0; k < F_IN; ++k) s += __bfloat162float(xr[k]) * Ms[k * F_OUT + c];
    } else {
        const float* xr = (const float*)x + (size_t)r * F_IN;
#pragma unroll
        for (int k = 0; k < F_IN; ++k) s += xr[k] * Ms[k * F_OUT + c];
    }
    stf(z, (size_t)r * F_OUT + c, isbf, s);
}
template <int LOGF>
__global__ __launch_bounds__(256) void k_init_acc(const int* __restrict__ flag,
                                                  const float* __restrict__ dinv,
                                                  const void* __restrict__ z,
                                                  float* __restrict__ acc, int base) {
    bool isbf = (*flag != 0);
    int t = blockIdx.x * 256 + threadIdx.x;
    int i = t >> LOGF, f = t & ((1 << LOGF) - 1);
    if (i >= N_NODES) return;
    float d = dinv[i];
    acc[t] = d * d * ldf(z, (size_t)i * F_OUT + base + f, isbf);
}
template <int LOGF>
__global__ __launch_bounds__(256) void k_scatter(const int* __restrict__ flag,
                                                 const int* __restrict__ ei,
                                                 const float* __restrict__ dinv,
                                                 const void* __restrict__ z,
                                                 float* __restrict__ acc, int base) {
    bool isbf = (*flag != 0);
    long long t = (long long)blockIdx.x * 256 + threadIdx.x;
    int e = (int)(t >> LOGF), f = (int)(t & ((1 << LOGF) - 1));
    if (e >= N_EDGES) return;
    int r = ei[e], c = ei[N_EDGES + e];
    float nm = dinv[r] * dinv[c];
    float v  = nm * ldf(z, (size_t)r * F_OUT + base + f, isbf);
    atomicAdd(&acc[((size_t)c << LOGF) + f], v);
}
template <int LOGF>
__global__ __launch_bounds__(256) void k_final(const int* __restrict__ flag,
                                               const float* __restrict__ acc,
                                               const float* __restrict__ cvec,
                                               void* __restrict__ out, int base) {
    bool isbf = (*flag != 0);
    int t = blockIdx.x * 256 + threadIdx.x;
    int i = t >> LOGF, f = t & ((1 << LOGF) - 1);
    if (i >= N_NODES) return;
    stf(out, (size_t)i * F_OUT + base + f, isbf, acc[t] + cvec[base + f]);
}
template <int LOGF>
static void run_passes(const int* flag, const int* ei, const float* dinv,
                       const void* z, float* acc, const float* cvec, void* out,
                       hipStream_t stream) {
    const int fpp = 1 << LOGF;
    const long long tn = (long long)N_NODES * fpp;
    const long long te = (long long)N_EDGES * fpp;
    const int gn = (int)((tn + 255) / 256);
    const int ge = (int)((te + 255) / 256);
    for (int base = 0; base < F_OUT; base += fpp) {
        k_init_acc<LOGF><<<gn, 256, 0, stream>>>(flag, dinv, z, acc, base);
        k_scatter<LOGF><<<ge, 256, 0, stream>>>(flag, ei, dinv, z, acc, base);
        k_final<LOGF><<<gn, 256, 0, stream>>>(flag, acc, cvec, out, base);
    }
}

extern "C" void kernel_launch(void* const* d_in, const int* in_sizes, int n_in,
                              void* d_out, int out_size, void* d_ws, size_t ws_size,
                              hipStream_t stream) {
    const void* x   = d_in[0];
    const int*  ei  = (const int*)d_in[1];
    const void* Wg  = d_in[2];
    const void* bg  = d_in[3];
    const void* Wf  = d_in[4];
    const void* bfc = d_in[5];
    char* ws = (char*)d_ws;

    const size_t CSR_NEED = 20838400;
    if (ws_size >= CSR_NEED) {
        int*      flag  = (int*)(ws + 0);
        float*    dinv  = (float*)(ws + 256);
        float*    M     = (float*)(ws + 400384);
        float*    cvec  = (float*)(ws + 433152);
        int*      cnt   = (int*)(ws + 433664);
        int*      ptr   = (int*)(ws + 833664);
        int*      gtail = (int*)(ws + 1233664);
        int*      bbase = (int*)(ws + 1234560);
        int*      srcs  = (int*)(ws + 1238528);
        bf16*     y     = (bf16*)(ws + 8038400);
        unsigned* bkt   = (unsigned*)(ws + 8038400);   // aliases y; dead before k_xmz

        k_detect<<<1, 64, 0, stream>>>((const unsigned short*)x, flag);
        k_zero<<<1, 256, 0, stream>>>(gtail);
        k_weights<<<(F_IN * F_OUT) / 256, 256, 0, stream>>>(flag, Wg, bg, Wf, bfc, M, cvec);
        k_binA<<<(N_EDGES + EPB_A - 1) / EPB_A, 256, 0, stream>>>(ei, gtail, bkt);
        k_bktscan<<<1, 256, 0, stream>>>(gtail, bbase);
        k_build<<<NB_BKT, 512, 0, stream>>>(bkt, gtail, bbase, ptr, cnt, dinv, srcs);
        k_xmz<<<(N_NODES + 63) / 64, 256, 0, stream>>>(flag, x, M, dinv, y);
        // 8 nodes per wave: 12500 waves = 3125 blocks of 256
        k_agg<<<3125, 256, 0, stream>>>(flag, ptr, cnt, srcs, dinv, y, cvec, d_out);
    } else {
        int*   flag = (int*)(ws + 0);
        float* deg  = (float*)(ws + 256);
        float* M    = (float*)(ws + 400384);
        float* cvec = (float*)(ws + 433152);
        float* acc  = (float*)(ws + 433664);

        k_detect<<<1, 64, 0, stream>>>((const unsigned short*)x, flag);
        k_init_deg<<<NBLK, 256, 0, stream>>>(deg);
        k_deg<<<N_EDGES / 256, 256, 0, stream>>>(ei + N_EDGES, deg);
        k_dinv<<<NBLK, 256, 0, stream>>>(deg);
        k_weights<<<(F_IN * F_OUT) / 256, 256, 0, stream>>>(flag, Wg, bg, Wf, bfc, M, cvec);
        k_xm<<<N_NODES / 4, 256, 0, stream>>>(flag, x, M, d_out);
        const size_t bn = 433664;
        if      (ws_size >= bn + (400000ull << 6)) run_passes<6>(flag, ei, deg, d_out, acc, cvec, d_out, stream);
        else if (ws_size >= bn + (400000ull << 5)) run_passes<5>(flag, ei, deg, d_out, acc, cvec, d_out, stream);
        else if (ws_size >= bn + (400000ull << 4)) run_passes<4>(flag, ei, deg, d_out, acc, cvec, d_out, stream);
        else if (ws_size >= bn + (400000ull << 3)) run_passes<3>(flag, ei, deg, d_out, acc, cvec, d_out, stream);
        else if (ws_size >= bn + (400000ull << 2)) run_passes<2>(flag, ei, deg, d_out, acc, cvec, d_out, stream);
        else if (ws_size >= bn + (400000ull << 1)) run_passes<1>(flag, ei, deg, d_out, acc, cvec, d_out, stream);
        else                                       run_passes<0>(flag, ei, deg, d_out, acc, cvec, d_out, stream);
    }
}